// Round 1
// baseline (1766.942 us; speedup 1.0000x reference)
//
#include <hip/hip_runtime.h>
#include <math.h>

#define NN 100000

__device__ __forceinline__ float sigmoidf_(float x){ return 1.0f/(1.0f+__expf(-x)); }

// ---------------- CSR build ----------------

__global__ void k_degrees(const int* __restrict__ src, const int* __restrict__ dst, int E,
                          int* __restrict__ deg_in, int* __restrict__ deg_out){
  for(int i = blockIdx.x*blockDim.x+threadIdx.x; i < E; i += gridDim.x*blockDim.x){
    atomicAdd(&deg_out[src[i]], 1);
    atomicAdd(&deg_in[dst[i]], 1);
  }
}

// inclusive scan per 1024-chunk
__global__ void k_scan_block(const int* __restrict__ in, int* __restrict__ incl, int* __restrict__ bsum){
  __shared__ int s[1024];
  int i = blockIdx.x*1024 + threadIdx.x;
  int v = (i < NN) ? in[i] : 0;
  s[threadIdx.x] = v; __syncthreads();
  for(int off=1; off<1024; off<<=1){
    int t = (threadIdx.x >= off) ? s[threadIdx.x-off] : 0;
    __syncthreads();
    s[threadIdx.x] += t;
    __syncthreads();
  }
  if(i < NN) incl[i] = s[threadIdx.x];
  if(threadIdx.x == 1023) bsum[blockIdx.x] = s[1023];
}

// exclusive scan of up to 128 block sums, single block of 128 threads
__global__ void k_scan_sums(const int* __restrict__ bsum, int* __restrict__ boff, int nb){
  __shared__ int s[128];
  int t = threadIdx.x;
  int v = (t < nb) ? bsum[t] : 0;
  s[t] = v; __syncthreads();
  for(int off=1; off<128; off<<=1){
    int u = (t >= off) ? s[t-off] : 0;
    __syncthreads();
    s[t] += u;
    __syncthreads();
  }
  boff[t] = s[t] - v;   // exclusive
}

__global__ void k_make_rowptr(const int* __restrict__ incl, const int* __restrict__ deg,
                              const int* __restrict__ boff, int* __restrict__ row_ptr){
  int i = blockIdx.x*blockDim.x + threadIdx.x;
  if(i < NN) row_ptr[i] = incl[i] - deg[i] + boff[i >> 10];
}

__global__ void k_fill_csr(const int* __restrict__ src, const int* __restrict__ dst, int E,
                           const int* __restrict__ row_ptr, int* __restrict__ cursor,
                           int* __restrict__ col){
  for(int i = blockIdx.x*blockDim.x+threadIdx.x; i < E; i += gridDim.x*blockDim.x){
    int d = dst[i];
    int p = atomicAdd(&cursor[d], 1);
    col[row_ptr[d] + p] = src[i];
  }
}

// ---------------- GraphConv layers ----------------

// x0[n] = in_degree(n) * rsqrt(max(deg_out,1))   (layer-1 input, pre-scaled)
__global__ void k_x0(const int* __restrict__ deg_in, const int* __restrict__ deg_out,
                     float* __restrict__ x0){
  int n = blockIdx.x*blockDim.x + threadIdx.x;
  if(n >= NN) return;
  int dou = deg_out[n];
  x0[n] = (float)deg_in[n] * rsqrtf((float)(dou > 1 ? dou : 1));
}

// a1[n] = rsqrt(max(deg_in,1)) * sum_{in-edges} x0[src]
__global__ void k_agg1(const float* __restrict__ x0, const int* __restrict__ row_ptr,
                       const int* __restrict__ deg_in, const int* __restrict__ col,
                       float* __restrict__ a1){
  int n = blockIdx.x*blockDim.x + threadIdx.x;
  if(n >= NN) return;
  int beg = row_ptr[n], d = deg_in[n];
  float r = 0.f;
  for(int e=0; e<d; e++) r += x0[col[beg+e]];
  a1[n] = r * rsqrtf((float)(d > 1 ? d : 1));
}

// h1s[n,j] = relu(a1[n]*W1[j]+b1[j]) * rsqrt(max(deg_out,1))
__global__ void k_expand1(const float* __restrict__ a1, const int* __restrict__ deg_out,
                          const float* __restrict__ W1, const float* __restrict__ b1,
                          float* __restrict__ hA){
  int gid = blockIdx.x*blockDim.x + threadIdx.x;
  int n = gid >> 6, j = gid & 63;
  if(n >= NN) return;
  float v = fmaxf(a1[n]*W1[j] + b1[j], 0.f);
  int dou = deg_out[n];
  hA[n*64 + j] = v * rsqrtf((float)(dou > 1 ? dou : 1));
}

// fused: aggregate 64-dim over in-edges, *rsqrt(deg_in), @W(64xOUTD)+b, opt relu, opt *rsqrt(deg_out)
template<int OUTD, bool RELU, bool PRESCALE>
__global__ void k_layer(const float* __restrict__ hin, const int* __restrict__ row_ptr,
                        const int* __restrict__ deg_in, const int* __restrict__ deg_out,
                        const int* __restrict__ col,
                        const float* __restrict__ W, const float* __restrict__ b,
                        float* __restrict__ hout){
  const int lane = threadIdx.x & 63;
  const int n = (blockIdx.x*blockDim.x + threadIdx.x) >> 6;   // one wave per node
  const int c = lane % OUTD;
  float Wreg[64];
  #pragma unroll
  for(int j=0;j<64;j++) Wreg[j] = W[j*OUTD + c];
  if(n >= NN) return;
  const int beg = row_ptr[n];
  const int d   = deg_in[n];
  float r = 0.f;
  for(int e=0; e<d; e++){
    int s = col[beg+e];
    r += hin[s*64 + lane];          // coalesced 256B per edge
  }
  float t = r * rsqrtf((float)(d > 1 ? d : 1));
  float acc = b[c];
  #pragma unroll
  for(int j=0;j<64;j++)
    acc += __shfl(t, j, 64) * Wreg[j];
  if(RELU) acc = fmaxf(acc, 0.f);
  if(PRESCALE){
    int dou = deg_out[n];
    acc *= rsqrtf((float)(dou > 1 ? dou : 1));
  }
  if(lane < OUTD) hout[n*OUTD + lane] = acc;
}

// ---------------- attention ----------------

__global__ void k_colmean(const float* __restrict__ f, float* __restrict__ mean_out){
  int t = threadIdx.x;
  int gid = blockIdx.x*blockDim.x + t;
  int dim = gid & 31;
  int node0 = gid >> 5;
  int nstride = (gridDim.x*blockDim.x) >> 5;
  float acc = 0.f;
  for(int n=node0; n<NN; n+=nstride) acc += f[n*32 + dim];
  __shared__ float red[256];
  red[t] = acc; __syncthreads();
  if(t < 32){
    float s = acc;
    for(int k=1;k<8;k++) s += red[t + 32*k];
    atomicAdd(&mean_out[t], s);
  }
}

__global__ void k_ctx(const float* __restrict__ mean_sum, const float* __restrict__ W_att,
                      float* __restrict__ ctx){
  int d = threadIdx.x;  // 32 threads
  float acc = 0.f;
  for(int i=0;i<32;i++) acc += (mean_sum[i]*(1.0f/(float)NN)) * W_att[i*32 + d];
  ctx[d] = tanhf(acc);
}

__global__ void k_scores_e(const float* __restrict__ f, const float* __restrict__ ctx,
                           float* __restrict__ e_out){
  int t = threadIdx.x;
  int gid = blockIdx.x*blockDim.x + t;
  int dim = gid & 31;
  int node0 = gid >> 5;
  int nstride = (gridDim.x*blockDim.x) >> 5;
  float c = ctx[dim];
  float acc = 0.f;
  for(int n=node0; n<NN; n+=nstride){
    float v = f[n*32 + dim];
    float d = v*c;
    d += __shfl_xor(d, 1);
    d += __shfl_xor(d, 2);
    d += __shfl_xor(d, 4);
    d += __shfl_xor(d, 8);
    d += __shfl_xor(d, 16);
    float sc = sigmoidf_(d);
    acc += v*sc;
  }
  __shared__ float red[256];
  red[t] = acc; __syncthreads();
  if(t < 32){
    float s = acc;
    for(int k=1;k<8;k++) s += red[t + 32*k];
    atomicAdd(&e_out[t], s);
  }
}

// ---------------- tiny head ----------------

__global__ void k_final(const float* __restrict__ e0, const float* __restrict__ e1,
                        const float* __restrict__ W_tn, const float* __restrict__ W_blk,
                        const float* __restrict__ b_tn, const float* __restrict__ W_fc,
                        const float* __restrict__ b_fc, const float* __restrict__ W_sc,
                        const float* __restrict__ b_sc, float* __restrict__ out){
  __shared__ float se0[32], se1[32], s_s[16], s2[16];
  int t = threadIdx.x;  // 64 threads
  if(t < 32){ se0[t] = e0[t]; se1[t] = e1[t]; }
  __syncthreads();
  if(t < 16){
    float sc = 0.f;
    for(int i=0;i<32;i++){
      float a = se0[i];
      for(int j=0;j<32;j++) sc += a * W_tn[(i*32 + j)*16 + t] * se1[j];
    }
    float bl = 0.f;
    for(int k=0;k<32;k++) bl += W_blk[t*64 + k]      * se0[k];
    for(int k=0;k<32;k++) bl += W_blk[t*64 + 32 + k] * se1[k];
    s_s[t] = fmaxf(sc + bl + b_tn[t], 0.f);
  }
  __syncthreads();
  if(t < 16){
    float a = 0.f;
    for(int k=0;k<16;k++) a += s_s[k]*W_fc[k*16 + t];
    s2[t] = fmaxf(a + b_fc[t], 0.f);
  }
  __syncthreads();
  if(t == 0){
    float a = 0.f;
    for(int k=0;k<16;k++) a += s2[k]*W_sc[k];
    out[0] = sigmoidf_(a + b_sc[0]);
  }
}

// ---------------- launch ----------------

extern "C" void kernel_launch(void* const* d_in, const int* in_sizes, int n_in,
                              void* d_out, int out_size, void* d_ws, size_t ws_size,
                              hipStream_t stream){
  const int* srcs[2] = { (const int*)d_in[0], (const int*)d_in[2] };
  const int* dsts[2] = { (const int*)d_in[1], (const int*)d_in[3] };
  const float* W1  = (const float*)d_in[4];
  const float* b1  = (const float*)d_in[5];
  const float* W2  = (const float*)d_in[6];
  const float* b2  = (const float*)d_in[7];
  const float* W3  = (const float*)d_in[8];
  const float* b3  = (const float*)d_in[9];
  const float* W_att = (const float*)d_in[10];
  const float* W_tn  = (const float*)d_in[11];
  const float* W_blk = (const float*)d_in[12];
  const float* b_tn  = (const float*)d_in[13];
  const float* W_fc  = (const float*)d_in[14];
  const float* b_fc  = (const float*)d_in[15];
  const float* W_sc  = (const float*)d_in[16];
  const float* b_sc  = (const float*)d_in[17];
  const int E = in_sizes[0];

  char* w = (char*)d_ws;
  size_t off = 0;
  auto alloc = [&](size_t bytes)->void*{ void* p = w + off; off += (bytes + 255)/256*256; return p; };
  int* deg_in  = (int*)alloc((size_t)NN*4);
  int* deg_out = (int*)alloc((size_t)NN*4);
  int* cursor  = (int*)alloc((size_t)NN*4);
  int* row_ptr = (int*)alloc((size_t)(NN+1)*4);
  int* tmp     = (int*)alloc((size_t)NN*4);
  int* bsum    = (int*)alloc(128*4);
  int* boff    = (int*)alloc(128*4);
  int* col     = (int*)alloc((size_t)E*4);
  float* x0    = (float*)alloc((size_t)NN*4);
  float* a1    = (float*)alloc((size_t)NN*4);
  float* hA    = (float*)alloc((size_t)NN*64*4);
  float* hB    = (float*)alloc((size_t)NN*64*4);
  float* mean  = (float*)alloc(32*4);
  float* ctx   = (float*)alloc(32*4);
  float* e0v   = (float*)alloc(32*4);
  float* e1v   = (float*)alloc(32*4);
  float* evec[2] = { e0v, e1v };

  const int nb = (NN + 1023)/1024;

  for(int g=0; g<2; ++g){
    const int* src = srcs[g];
    const int* dst = dsts[g];
    hipMemsetAsync(deg_in, 0, (size_t)NN*4, stream);
    hipMemsetAsync(deg_out, 0, (size_t)NN*4, stream);
    hipMemsetAsync(cursor, 0, (size_t)NN*4, stream);
    hipMemsetAsync(mean,   0, 32*4, stream);
    hipMemsetAsync(evec[g],0, 32*4, stream);

    k_degrees<<<2048,256,0,stream>>>(src,dst,E,deg_in,deg_out);
    k_scan_block<<<nb,1024,0,stream>>>(deg_in,tmp,bsum);
    k_scan_sums<<<1,128,0,stream>>>(bsum,boff,nb);
    k_make_rowptr<<<(NN+255)/256,256,0,stream>>>(tmp,deg_in,boff,row_ptr);
    k_fill_csr<<<2048,256,0,stream>>>(src,dst,E,row_ptr,cursor,col);

    k_x0<<<(NN+255)/256,256,0,stream>>>(deg_in,deg_out,x0);
    k_agg1<<<(NN+255)/256,256,0,stream>>>(x0,row_ptr,deg_in,col,a1);
    k_expand1<<<(NN*64)/256,256,0,stream>>>(a1,deg_out,W1,b1,hA);

    k_layer<64,true,true ><<<NN/4,256,0,stream>>>(hA,row_ptr,deg_in,deg_out,col,W2,b2,hB);
    k_layer<32,false,false><<<NN/4,256,0,stream>>>(hB,row_ptr,deg_in,deg_out,col,W3,b3,hA);

    k_colmean<<<512,256,0,stream>>>(hA,mean);
    k_ctx<<<1,32,0,stream>>>(mean,W_att,ctx);
    k_scores_e<<<512,256,0,stream>>>(hA,ctx,evec[g]);
  }
  k_final<<<1,64,0,stream>>>(evec[0],evec[1],W_tn,W_blk,b_tn,W_fc,b_fc,W_sc,b_sc,(float*)d_out);
}

// Round 2
// 1110.209 us; speedup vs baseline: 1.5915x; 1.5915x over previous
//
#include <hip/hip_runtime.h>
#include <math.h>

#define NN 100000
#define TWO_N 200000

struct __align__(4) h2_t { _Float16 x, y; };

__device__ __forceinline__ float sigmoidf_(float x){ return 1.0f/(1.0f+__expf(-x)); }

// ---------------- CSR build (batched: graph0 then graph1) ----------------

__global__ void k_degrees(const int* __restrict__ s0, const int* __restrict__ d0,
                          const int* __restrict__ s1, const int* __restrict__ d1, int E,
                          int* __restrict__ deg_in, int* __restrict__ deg_out){
  for(int i = blockIdx.x*blockDim.x+threadIdx.x; i < 2*E; i += gridDim.x*blockDim.x){
    int g = (i >= E); int le = g ? i - E : i;
    int sv = g ? s1[le] : s0[le];
    int dv = g ? d1[le] : d0[le];
    atomicAdd(&deg_out[g*NN + sv], 1);
    atomicAdd(&deg_in [g*NN + dv], 1);
  }
}

__global__ void k_scan_block(const int* __restrict__ in, int* __restrict__ incl, int* __restrict__ bsum){
  __shared__ int s[1024];
  int i = blockIdx.x*1024 + threadIdx.x;
  int v = (i < TWO_N) ? in[i] : 0;
  s[threadIdx.x] = v; __syncthreads();
  for(int off=1; off<1024; off<<=1){
    int t = (threadIdx.x >= off) ? s[threadIdx.x-off] : 0;
    __syncthreads();
    s[threadIdx.x] += t;
    __syncthreads();
  }
  if(i < TWO_N) incl[i] = s[threadIdx.x];
  if(threadIdx.x == 1023) bsum[blockIdx.x] = s[1023];
}

__global__ void k_scan_sums(const int* __restrict__ bsum, int* __restrict__ boff, int nb){
  __shared__ int s[256];
  int t = threadIdx.x;
  int v = (t < nb) ? bsum[t] : 0;
  s[t] = v; __syncthreads();
  for(int off=1; off<256; off<<=1){
    int u = (t >= off) ? s[t-off] : 0;
    __syncthreads();
    s[t] += u;
    __syncthreads();
  }
  boff[t] = s[t] - v;   // exclusive
}

__global__ void k_make_rowptr(const int* __restrict__ incl, const int* __restrict__ deg,
                              const int* __restrict__ boff, int* __restrict__ row_ptr){
  int i = blockIdx.x*blockDim.x + threadIdx.x;
  if(i < TWO_N) row_ptr[i] = incl[i] - deg[i] + boff[i >> 10];
}

__global__ void k_fill(const int* __restrict__ s0, const int* __restrict__ d0,
                       const int* __restrict__ s1, const int* __restrict__ d1, int E,
                       const int* __restrict__ row_ptr, int* __restrict__ cursor,
                       int* __restrict__ col){
  for(int i = blockIdx.x*blockDim.x+threadIdx.x; i < 2*E; i += gridDim.x*blockDim.x){
    int g = (i >= E); int le = g ? i - E : i;
    int dv = g ? d1[le] : d0[le];
    int sv = g ? s1[le] : s0[le];
    int gn = g*NN + dv;
    int p = atomicAdd(&cursor[gn], 1);
    col[row_ptr[gn] + p] = g*NN + sv;   // store GLOBAL src id
  }
}

__global__ void k_x0(const int* __restrict__ deg_in, const int* __restrict__ deg_out,
                     float* __restrict__ x0){
  int n = blockIdx.x*blockDim.x + threadIdx.x;
  if(n >= TWO_N) return;
  int dou = deg_out[n];
  x0[n] = (float)deg_in[n] * rsqrtf((float)(dou > 1 ? dou : 1));
}

// ---------------- fused layer kernels (wave per node) ----------------

// layer1 (scalar gather) + layer1 epilogue + pre-apply W2  ->  g2h fp16 [2N][64]
__global__ void k_g1(const float* __restrict__ x0, const int* __restrict__ row_ptr,
                     const int* __restrict__ deg_in, const int* __restrict__ deg_out,
                     const int* __restrict__ col,
                     const float* __restrict__ W1, const float* __restrict__ b1,
                     const float* __restrict__ W2, _Float16* __restrict__ g2h){
  __shared__ float W2s[64*64];
  __shared__ float W1s[64], b1s[64];
  int t = threadIdx.x;
  for(int i=t; i<64*64; i+=blockDim.x) W2s[i] = W2[i];
  if(t < 64){ W1s[t] = W1[t]; b1s[t] = b1[t]; }
  __syncthreads();
  int wid = (blockIdx.x*blockDim.x + t) >> 6;
  int lane = t & 63;
  if(wid >= TWO_N) return;
  int beg = row_ptr[wid], d = deg_in[wid];
  float r = 0.f;
  for(int e=lane; e<d; e+=64) r += x0[col[beg+e]];
  r += __shfl_xor(r,1); r += __shfl_xor(r,2); r += __shfl_xor(r,4);
  r += __shfl_xor(r,8); r += __shfl_xor(r,16); r += __shfl_xor(r,32);
  float agg1 = r * rsqrtf((float)(d > 1 ? d : 1));
  int dou = deg_out[wid];
  float rs_out = rsqrtf((float)(dou > 1 ? dou : 1));
  float h1 = fmaxf(agg1*W1s[lane] + b1s[lane], 0.f) * rs_out;
  float acc = 0.f;
  #pragma unroll
  for(int k=0;k<64;k++) acc += __shfl(h1, k) * W2s[k*64 + lane];
  g2h[(size_t)wid*64 + lane] = (_Float16)acc;
}

// layer2: 64-dim fp16 gather (2 edges/iter) + epilogue + pre-apply W3 -> g3h fp16 [2N][32]
__global__ void k_g2(const _Float16* __restrict__ g2h, const int* __restrict__ row_ptr,
                     const int* __restrict__ deg_in, const int* __restrict__ deg_out,
                     const int* __restrict__ col,
                     const float* __restrict__ b2, const float* __restrict__ W3,
                     _Float16* __restrict__ g3h){
  __shared__ float W3s[64*32];
  __shared__ float b2s[64];
  int t = threadIdx.x;
  for(int i=t; i<64*32; i+=blockDim.x) W3s[i] = W3[i];
  if(t < 64) b2s[t] = b2[t];
  __syncthreads();
  int wid = (blockIdx.x*blockDim.x + t) >> 6;
  int lane = t & 63;
  if(wid >= TWO_N) return;
  int beg = row_ptr[wid], d = deg_in[wid];
  int sub = lane >> 5, p = lane & 31;
  float ax = 0.f, ay = 0.f;
  #pragma unroll 2
  for(int e=sub; e<d; e+=2){
    int s = col[beg+e];
    h2_t v = *(const h2_t*)(g2h + (size_t)s*64 + p*2);
    ax += (float)v.x; ay += (float)v.y;
  }
  ax += __shfl_xor(ax,32); ay += __shfl_xor(ay,32);
  float rs_in = rsqrtf((float)(d > 1 ? d : 1));
  int dou = deg_out[wid];
  float rs_out = rsqrtf((float)(dou > 1 ? dou : 1));
  float hx = fmaxf(ax*rs_in + b2s[2*p  ], 0.f) * rs_out;
  float hy = fmaxf(ay*rs_in + b2s[2*p+1], 0.f) * rs_out;
  float acc = 0.f;
  int j = lane & 31;
  #pragma unroll
  for(int k=0;k<64;k+=2){
    acc += __shfl(hx, k>>1) * W3s[ k   *32 + j];
    acc += __shfl(hy, k>>1) * W3s[(k+1)*32 + j];
  }
  if(lane < 32) g3h[(size_t)wid*32 + j] = (_Float16)acc;
}

// layer3: 32-dim fp16 gather (4 edges/iter) + epilogue -> f fp16 [2N][32]
__global__ void k_g3(const _Float16* __restrict__ g3h, const int* __restrict__ row_ptr,
                     const int* __restrict__ deg_in, const int* __restrict__ col,
                     const float* __restrict__ b3, _Float16* __restrict__ f){
  int t = threadIdx.x;
  int wid = (blockIdx.x*blockDim.x + t) >> 6;
  int lane = t & 63;
  if(wid >= TWO_N) return;
  int beg = row_ptr[wid], d = deg_in[wid];
  int sub = lane >> 4, p = lane & 15;
  float ax = 0.f, ay = 0.f;
  #pragma unroll 2
  for(int e=sub; e<d; e+=4){
    int s = col[beg+e];
    h2_t v = *(const h2_t*)(g3h + (size_t)s*32 + p*2);
    ax += (float)v.x; ay += (float)v.y;
  }
  ax += __shfl_xor(ax,32); ay += __shfl_xor(ay,32);
  ax += __shfl_xor(ax,16); ay += __shfl_xor(ay,16);
  float rs_in = rsqrtf((float)(d > 1 ? d : 1));
  if(lane < 16){
    h2_t o;
    o.x = (_Float16)(ax*rs_in + b3[2*p  ]);
    o.y = (_Float16)(ay*rs_in + b3[2*p+1]);
    *(h2_t*)(f + (size_t)wid*32 + p*2) = o;
  }
}

// ---------------- attention (batched) ----------------

__global__ void k_colmean(const _Float16* __restrict__ f, float* __restrict__ mean){
  int g = blockIdx.x >> 8;           // 256 blocks per graph
  int t = threadIdx.x;
  int p = t & 15;                    // dim pair
  int nodeLane = ((blockIdx.x & 255) << 4) | (t >> 4);  // 0..4095
  float ax = 0.f, ay = 0.f;
  for(int n=nodeLane; n<NN; n+=4096){
    h2_t v = *(const h2_t*)(f + ((size_t)(g*NN + n))*32 + p*2);
    ax += (float)v.x; ay += (float)v.y;
  }
  __shared__ float sx[256], sy[256];
  sx[t] = ax; sy[t] = ay; __syncthreads();
  if(t < 16){
    float rx = 0.f, ry = 0.f;
    for(int k=0;k<16;k++){ rx += sx[k*16+t]; ry += sy[k*16+t]; }
    atomicAdd(&mean[g*32 + 2*t    ], rx);
    atomicAdd(&mean[g*32 + 2*t + 1], ry);
  }
}

__global__ void k_ctx(const float* __restrict__ mean, const float* __restrict__ W_att,
                      float* __restrict__ ctx){
  int t = threadIdx.x;   // 64 threads: 2 graphs x 32 dims
  int g = t >> 5, d = t & 31;
  float acc = 0.f;
  for(int i=0;i<32;i++) acc += (mean[g*32+i] * (1.0f/(float)NN)) * W_att[i*32 + d];
  ctx[t] = tanhf(acc);
}

__global__ void k_scores(const _Float16* __restrict__ f, const float* __restrict__ ctx,
                         float* __restrict__ evec){
  int g = blockIdx.x >> 8;
  int t = threadIdx.x;
  int p = t & 15;
  int nodeLane = ((blockIdx.x & 255) << 4) | (t >> 4);
  float cx = ctx[g*32 + 2*p], cy = ctx[g*32 + 2*p + 1];
  float ax = 0.f, ay = 0.f;
  for(int n=nodeLane; n<NN; n+=4096){
    h2_t v = *(const h2_t*)(f + ((size_t)(g*NN + n))*32 + p*2);
    float vx = (float)v.x, vy = (float)v.y;
    float dt = vx*cx + vy*cy;
    dt += __shfl_xor(dt,1); dt += __shfl_xor(dt,2);
    dt += __shfl_xor(dt,4); dt += __shfl_xor(dt,8);
    float sc = sigmoidf_(dt);
    ax += vx*sc; ay += vy*sc;
  }
  __shared__ float sx[256], sy[256];
  sx[t] = ax; sy[t] = ay; __syncthreads();
  if(t < 16){
    float rx = 0.f, ry = 0.f;
    for(int k=0;k<16;k++){ rx += sx[k*16+t]; ry += sy[k*16+t]; }
    atomicAdd(&evec[g*32 + 2*t    ], rx);
    atomicAdd(&evec[g*32 + 2*t + 1], ry);
  }
}

// ---------------- tiny head ----------------

__global__ void k_final(const float* __restrict__ evec,
                        const float* __restrict__ W_tn, const float* __restrict__ W_blk,
                        const float* __restrict__ b_tn, const float* __restrict__ W_fc,
                        const float* __restrict__ b_fc, const float* __restrict__ W_sc,
                        const float* __restrict__ b_sc, float* __restrict__ out){
  __shared__ float se0[32], se1[32], s_s[16], s2[16];
  int t = threadIdx.x;  // 64 threads
  if(t < 32){ se0[t] = evec[t]; se1[t] = evec[32 + t]; }
  __syncthreads();
  if(t < 16){
    float sc = 0.f;
    for(int i=0;i<32;i++){
      float a = se0[i];
      for(int j=0;j<32;j++) sc += a * W_tn[(i*32 + j)*16 + t] * se1[j];
    }
    float bl = 0.f;
    for(int k=0;k<32;k++) bl += W_blk[t*64 + k]      * se0[k];
    for(int k=0;k<32;k++) bl += W_blk[t*64 + 32 + k] * se1[k];
    s_s[t] = fmaxf(sc + bl + b_tn[t], 0.f);
  }
  __syncthreads();
  if(t < 16){
    float a = 0.f;
    for(int k=0;k<16;k++) a += s_s[k]*W_fc[k*16 + t];
    s2[t] = fmaxf(a + b_fc[t], 0.f);
  }
  __syncthreads();
  if(t == 0){
    float a = 0.f;
    for(int k=0;k<16;k++) a += s2[k]*W_sc[k];
    out[0] = sigmoidf_(a + b_sc[0]);
  }
}

// ---------------- launch ----------------

extern "C" void kernel_launch(void* const* d_in, const int* in_sizes, int n_in,
                              void* d_out, int out_size, void* d_ws, size_t ws_size,
                              hipStream_t stream){
  const int* s0 = (const int*)d_in[0];
  const int* dd0 = (const int*)d_in[1];
  const int* s1 = (const int*)d_in[2];
  const int* dd1 = (const int*)d_in[3];
  const float* W1  = (const float*)d_in[4];
  const float* b1  = (const float*)d_in[5];
  const float* W2  = (const float*)d_in[6];
  const float* b2  = (const float*)d_in[7];
  const float* W3  = (const float*)d_in[8];
  const float* b3  = (const float*)d_in[9];
  const float* W_att = (const float*)d_in[10];
  const float* W_tn  = (const float*)d_in[11];
  const float* W_blk = (const float*)d_in[12];
  const float* b_tn  = (const float*)d_in[13];
  const float* W_fc  = (const float*)d_in[14];
  const float* b_fc  = (const float*)d_in[15];
  const float* W_sc  = (const float*)d_in[16];
  const float* b_sc  = (const float*)d_in[17];
  const int E = in_sizes[0];

  char* w = (char*)d_ws;
  size_t off = 0;
  auto alloc = [&](size_t bytes)->void*{ void* p = w + off; off += (bytes + 255)/256*256; return p; };
  // zeroed region (one memset): deg_in, deg_out, cursor, mean, evec
  int*   deg_in  = (int*)alloc((size_t)TWO_N*4);
  int*   deg_out = (int*)alloc((size_t)TWO_N*4);
  int*   cursor  = (int*)alloc((size_t)TWO_N*4);
  float* mean    = (float*)alloc(64*4);
  float* evec    = (float*)alloc(64*4);
  size_t zero_bytes = off;
  int*   row_ptr = (int*)alloc((size_t)TWO_N*4);
  int*   bsum    = (int*)alloc(256*4);
  int*   boff    = (int*)alloc(256*4);
  int*   col     = (int*)alloc((size_t)2*E*4);
  float* x0      = (float*)alloc((size_t)TWO_N*4);
  _Float16* g2h  = (_Float16*)alloc((size_t)TWO_N*64*2);
  _Float16* g3h  = (_Float16*)alloc((size_t)TWO_N*32*2);
  _Float16* f    = (_Float16*)alloc((size_t)TWO_N*32*2);
  float* ctx     = (float*)alloc(64*4);
  int*   tmp     = (int*)g2h;   // scan scratch, dead before g2h is written

  hipMemsetAsync(d_ws, 0, zero_bytes, stream);

  const int nb = (TWO_N + 1023)/1024;   // 196
  k_degrees<<<4096,256,0,stream>>>(s0,dd0,s1,dd1,E,deg_in,deg_out);
  k_scan_block<<<nb,1024,0,stream>>>(deg_in,tmp,bsum);
  k_scan_sums<<<1,256,0,stream>>>(bsum,boff,nb);
  k_make_rowptr<<<(TWO_N+255)/256,256,0,stream>>>(tmp,deg_in,boff,row_ptr);
  k_fill<<<4096,256,0,stream>>>(s0,dd0,s1,dd1,E,row_ptr,cursor,col);

  k_x0<<<(TWO_N+255)/256,256,0,stream>>>(deg_in,deg_out,x0);

  const int WPB = 4;  // waves (nodes) per 256-thread block
  k_g1<<<TWO_N/WPB,256,0,stream>>>(x0,row_ptr,deg_in,deg_out,col,W1,b1,W2,g2h);
  k_g2<<<TWO_N/WPB,256,0,stream>>>(g2h,row_ptr,deg_in,deg_out,col,b2,W3,g3h);
  k_g3<<<TWO_N/WPB,256,0,stream>>>(g3h,row_ptr,deg_in,col,b3,f);

  k_colmean<<<512,256,0,stream>>>(f,mean);
  k_ctx<<<1,64,0,stream>>>(mean,W_att,ctx);
  k_scores<<<512,256,0,stream>>>(f,ctx,evec);

  k_final<<<1,64,0,stream>>>(evec,W_tn,W_blk,b_tn,W_fc,b_fc,W_sc,b_sc,(float*)d_out);
}

// Round 3
// 975.771 us; speedup vs baseline: 1.8108x; 1.1378x over previous
//
#include <hip/hip_runtime.h>
#include <math.h>

#define NN 100000
#define TWO_N 200000

struct __align__(4) h2_t { _Float16 x, y; };
struct __align__(8) h4_t { _Float16 v[4]; };

__device__ __forceinline__ float sigmoidf_(float x){ return 1.0f/(1.0f+__expf(-x)); }

// ---------------- CSR build (batched: graph0 then graph1) ----------------

__global__ void k_degrees(const int* __restrict__ s0, const int* __restrict__ d0,
                          const int* __restrict__ s1, const int* __restrict__ d1, int E,
                          int* __restrict__ deg_in, int* __restrict__ deg_out){
  for(int i = blockIdx.x*blockDim.x+threadIdx.x; i < 2*E; i += gridDim.x*blockDim.x){
    int g = (i >= E); int le = g ? i - E : i;
    int sv = g ? s1[le] : s0[le];
    int dv = g ? d1[le] : d0[le];
    atomicAdd(&deg_out[g*NN + sv], 1);
    atomicAdd(&deg_in [g*NN + dv], 1);
  }
}

__global__ void k_scan_block(const int* __restrict__ in, int* __restrict__ incl, int* __restrict__ bsum){
  __shared__ int s[1024];
  int i = blockIdx.x*1024 + threadIdx.x;
  int v = (i < TWO_N) ? in[i] : 0;
  s[threadIdx.x] = v; __syncthreads();
  for(int off=1; off<1024; off<<=1){
    int t = (threadIdx.x >= off) ? s[threadIdx.x-off] : 0;
    __syncthreads();
    s[threadIdx.x] += t;
    __syncthreads();
  }
  if(i < TWO_N) incl[i] = s[threadIdx.x];
  if(threadIdx.x == 1023) bsum[blockIdx.x] = s[1023];
}

__global__ void k_scan_sums(const int* __restrict__ bsum, int* __restrict__ boff, int nb){
  __shared__ int s[256];
  int t = threadIdx.x;
  int v = (t < nb) ? bsum[t] : 0;
  s[t] = v; __syncthreads();
  for(int off=1; off<256; off<<=1){
    int u = (t >= off) ? s[t-off] : 0;
    __syncthreads();
    s[t] += u;
    __syncthreads();
  }
  boff[t] = s[t] - v;   // exclusive
}

__global__ void k_make_rowptr(const int* __restrict__ incl, const int* __restrict__ deg,
                              const int* __restrict__ boff, int* __restrict__ row_ptr){
  int i = blockIdx.x*blockDim.x + threadIdx.x;
  if(i < TWO_N) row_ptr[i] = incl[i] - deg[i] + boff[i >> 10];
}

__global__ void k_fill(const int* __restrict__ s0, const int* __restrict__ d0,
                       const int* __restrict__ s1, const int* __restrict__ d1, int E,
                       const int* __restrict__ row_ptr, int* __restrict__ cursor,
                       int* __restrict__ col){
  for(int i = blockIdx.x*blockDim.x+threadIdx.x; i < 2*E; i += gridDim.x*blockDim.x){
    int g = (i >= E); int le = g ? i - E : i;
    int dv = g ? d1[le] : d0[le];
    int sv = g ? s1[le] : s0[le];
    int gn = g*NN + dv;
    int p = atomicAdd(&cursor[gn], 1);
    col[row_ptr[gn] + p] = g*NN + sv;   // GLOBAL src id
  }
}

__global__ void k_x0(const int* __restrict__ deg_in, const int* __restrict__ deg_out,
                     float* __restrict__ x0){
  int n = blockIdx.x*blockDim.x + threadIdx.x;
  if(n >= TWO_N) return;
  int dou = deg_out[n];
  x0[n] = (float)deg_in[n] * rsqrtf((float)(dou > 1 ? dou : 1));
}

// ---------------- layer kernels ----------------

// layer-1 aggregation only: av[n] = { a_n, rs_out_n }  (fp16 pair, 4B)
//   a_n = rs_in(n) * sum_{s in N(n)} x0[s]
__global__ void k_g1(const float* __restrict__ x0, const int* __restrict__ row_ptr,
                     const int* __restrict__ deg_in, const int* __restrict__ deg_out,
                     const int* __restrict__ col, h2_t* __restrict__ av){
  int t = threadIdx.x;
  int wid = (blockIdx.x*blockDim.x + t) >> 6;
  int lane = t & 63;
  if(wid >= TWO_N) return;
  int beg = row_ptr[wid], d = deg_in[wid];
  float r = 0.f;
  for(int e=lane; e<d; e+=64) r += x0[col[beg+e]];
  r += __shfl_xor(r,1); r += __shfl_xor(r,2); r += __shfl_xor(r,4);
  r += __shfl_xor(r,8); r += __shfl_xor(r,16); r += __shfl_xor(r,32);
  if(lane == 0){
    float a = r * rsqrtf((float)(d > 1 ? d : 1));
    int dou = deg_out[wid];
    h2_t o;
    o.x = (_Float16)a;
    o.y = (_Float16)rsqrtf((float)(dou > 1 ? dou : 1));
    av[wid] = o;
  }
}

// layer 2 with direct recomputation of h1 from scalars:
//  acc_j = sum_s relu(a_s*W1[j]+b1[j])*rs_s   (gather 4B/edge from 800KB table)
//  agg2_j = acc_j*rs_in;  h2_j = relu(agg2@W2 + b2)*rs_out;  g3h = h2@W3 (fp16, 32)
__global__ void k_g2(const h2_t* __restrict__ av, const int* __restrict__ row_ptr,
                     const int* __restrict__ deg_in, const int* __restrict__ deg_out,
                     const int* __restrict__ col,
                     const float* __restrict__ W1, const float* __restrict__ b1,
                     const float* __restrict__ W2, const float* __restrict__ b2,
                     const float* __restrict__ W3, _Float16* __restrict__ g3h){
  __shared__ float W2s[64*64];
  __shared__ float W3s[64*32];
  __shared__ float W1s[64], b1s[64], b2s[64];
  int t = threadIdx.x;
  for(int i=t; i<64*64; i+=blockDim.x) W2s[i] = W2[i];
  for(int i=t; i<64*32; i+=blockDim.x) W3s[i] = W3[i];
  if(t < 64){ W1s[t] = W1[t]; b1s[t] = b1[t]; b2s[t] = b2[t]; }
  __syncthreads();
  int wid = (blockIdx.x*blockDim.x + t) >> 6;
  int lane = t & 63;
  if(wid >= TWO_N) return;
  int beg = row_ptr[wid], d = deg_in[wid];
  float W1j = W1s[lane], b1j = b1s[lane];
  float acc = 0.f;
  for(int base=0; base<d; base+=64){
    int cnt = min(64, d - base);
    unsigned pk = 0u;
    int idx = base + lane;
    if(idx < d) pk = *(const unsigned*)&av[col[beg+idx]];
    for(int k=0;k<cnt;k++){
      union { unsigned u; h2_t h; } cv; cv.u = __shfl(pk, k);
      float a  = (float)cv.h.x;
      float rs = (float)cv.h.y;
      float h1 = fmaxf(fmaf(a, W1j, b1j), 0.f);
      acc = fmaf(h1, rs, acc);
    }
  }
  float agg2 = acc * rsqrtf((float)(d > 1 ? d : 1));
  // h2 = relu(agg2 @ W2 + b2) * rs_out
  float acc2 = b2s[lane];
  #pragma unroll
  for(int k=0;k<64;k++) acc2 = fmaf(__shfl(agg2, k), W2s[k*64 + lane], acc2);
  int dou = deg_out[wid];
  float h2 = fmaxf(acc2, 0.f) * rsqrtf((float)(dou > 1 ? dou : 1));
  // g3h = h2 @ W3  (split halves across lane>=32)
  int j32 = lane & 31, sub = lane >> 5;
  float acc3 = 0.f;
  #pragma unroll
  for(int k=0;k<32;k++){
    int kk = sub*32 + k;
    acc3 = fmaf(__shfl(h2, kk), W3s[kk*32 + j32], acc3);
  }
  acc3 += __shfl_xor(acc3, 32);
  if(lane < 32) g3h[(size_t)wid*32 + j32] = (_Float16)acc3;
}

// layer3: 32-dim fp16 gather, 8 lanes/edge (float2), 8 edges/iter -> f fp16 [2N][32]
__global__ void k_g3(const _Float16* __restrict__ g3h, const int* __restrict__ row_ptr,
                     const int* __restrict__ deg_in, const int* __restrict__ col,
                     const float* __restrict__ b3, _Float16* __restrict__ f){
  int t = threadIdx.x;
  int wid = (blockIdx.x*blockDim.x + t) >> 6;
  int lane = t & 63;
  if(wid >= TWO_N) return;
  int beg = row_ptr[wid], d = deg_in[wid];
  int q = lane >> 3, p = lane & 7;
  float a0=0.f, a1=0.f, a2=0.f, a3=0.f;
  #pragma unroll 2
  for(int e=q; e<d; e+=8){
    int s = col[beg+e];
    float2 v = *(const float2*)(g3h + (size_t)s*32 + p*4);
    union { float f; h2_t h; } u0, u1;
    u0.f = v.x; u1.f = v.y;
    a0 += (float)u0.h.x; a1 += (float)u0.h.y;
    a2 += (float)u1.h.x; a3 += (float)u1.h.y;
  }
  #pragma unroll
  for(int m=8; m<64; m<<=1){
    a0 += __shfl_xor(a0,m); a1 += __shfl_xor(a1,m);
    a2 += __shfl_xor(a2,m); a3 += __shfl_xor(a3,m);
  }
  if(lane < 8){
    float rs = rsqrtf((float)(d > 1 ? d : 1));
    h4_t o;
    o.v[0] = (_Float16)(a0*rs + b3[p*4+0]);
    o.v[1] = (_Float16)(a1*rs + b3[p*4+1]);
    o.v[2] = (_Float16)(a2*rs + b3[p*4+2]);
    o.v[3] = (_Float16)(a3*rs + b3[p*4+3]);
    *(h4_t*)(f + (size_t)wid*32 + p*4) = o;
  }
}

// ---------------- attention (batched) ----------------

__global__ void k_colmean(const _Float16* __restrict__ f, float* __restrict__ mean){
  int g = blockIdx.x >> 8;
  int t = threadIdx.x;
  int p = t & 15;
  int nodeLane = ((blockIdx.x & 255) << 4) | (t >> 4);
  float ax = 0.f, ay = 0.f;
  for(int n=nodeLane; n<NN; n+=4096){
    h2_t v = *(const h2_t*)(f + ((size_t)(g*NN + n))*32 + p*2);
    ax += (float)v.x; ay += (float)v.y;
  }
  __shared__ float sx[256], sy[256];
  sx[t] = ax; sy[t] = ay; __syncthreads();
  if(t < 16){
    float rx = 0.f, ry = 0.f;
    for(int k=0;k<16;k++){ rx += sx[k*16+t]; ry += sy[k*16+t]; }
    atomicAdd(&mean[g*32 + 2*t    ], rx);
    atomicAdd(&mean[g*32 + 2*t + 1], ry);
  }
}

__global__ void k_ctx(const float* __restrict__ mean, const float* __restrict__ W_att,
                      float* __restrict__ ctx){
  int t = threadIdx.x;   // 64 threads: 2 graphs x 32 dims
  int g = t >> 5, d = t & 31;
  float acc = 0.f;
  for(int i=0;i<32;i++) acc += (mean[g*32+i] * (1.0f/(float)NN)) * W_att[i*32 + d];
  ctx[t] = tanhf(acc);
}

__global__ void k_scores(const _Float16* __restrict__ f, const float* __restrict__ ctx,
                         float* __restrict__ evec){
  int g = blockIdx.x >> 8;
  int t = threadIdx.x;
  int p = t & 15;
  int nodeLane = ((blockIdx.x & 255) << 4) | (t >> 4);
  float cx = ctx[g*32 + 2*p], cy = ctx[g*32 + 2*p + 1];
  float ax = 0.f, ay = 0.f;
  for(int n=nodeLane; n<NN; n+=4096){
    h2_t v = *(const h2_t*)(f + ((size_t)(g*NN + n))*32 + p*2);
    float vx = (float)v.x, vy = (float)v.y;
    float dt = vx*cx + vy*cy;
    dt += __shfl_xor(dt,1); dt += __shfl_xor(dt,2);
    dt += __shfl_xor(dt,4); dt += __shfl_xor(dt,8);
    float sc = sigmoidf_(dt);
    ax += vx*sc; ay += vy*sc;
  }
  __shared__ float sx[256], sy[256];
  sx[t] = ax; sy[t] = ay; __syncthreads();
  if(t < 16){
    float rx = 0.f, ry = 0.f;
    for(int k=0;k<16;k++){ rx += sx[k*16+t]; ry += sy[k*16+t]; }
    atomicAdd(&evec[g*32 + 2*t    ], rx);
    atomicAdd(&evec[g*32 + 2*t + 1], ry);
  }
}

// ---------------- tiny head ----------------

__global__ void k_final(const float* __restrict__ evec,
                        const float* __restrict__ W_tn, const float* __restrict__ W_blk,
                        const float* __restrict__ b_tn, const float* __restrict__ W_fc,
                        const float* __restrict__ b_fc, const float* __restrict__ W_sc,
                        const float* __restrict__ b_sc, float* __restrict__ out){
  __shared__ float se0[32], se1[32], s_s[16], s2[16];
  int t = threadIdx.x;  // 64 threads
  if(t < 32){ se0[t] = evec[t]; se1[t] = evec[32 + t]; }
  __syncthreads();
  if(t < 16){
    float sc = 0.f;
    for(int i=0;i<32;i++){
      float a = se0[i];
      for(int j=0;j<32;j++) sc += a * W_tn[(i*32 + j)*16 + t] * se1[j];
    }
    float bl = 0.f;
    for(int k=0;k<32;k++) bl += W_blk[t*64 + k]      * se0[k];
    for(int k=0;k<32;k++) bl += W_blk[t*64 + 32 + k] * se1[k];
    s_s[t] = fmaxf(sc + bl + b_tn[t], 0.f);
  }
  __syncthreads();
  if(t < 16){
    float a = 0.f;
    for(int k=0;k<16;k++) a += s_s[k]*W_fc[k*16 + t];
    s2[t] = fmaxf(a + b_fc[t], 0.f);
  }
  __syncthreads();
  if(t == 0){
    float a = 0.f;
    for(int k=0;k<16;k++) a += s2[k]*W_sc[k];
    out[0] = sigmoidf_(a + b_sc[0]);
  }
}

// ---------------- launch ----------------

extern "C" void kernel_launch(void* const* d_in, const int* in_sizes, int n_in,
                              void* d_out, int out_size, void* d_ws, size_t ws_size,
                              hipStream_t stream){
  const int* s0 = (const int*)d_in[0];
  const int* dd0 = (const int*)d_in[1];
  const int* s1 = (const int*)d_in[2];
  const int* dd1 = (const int*)d_in[3];
  const float* W1  = (const float*)d_in[4];
  const float* b1  = (const float*)d_in[5];
  const float* W2  = (const float*)d_in[6];
  const float* b2  = (const float*)d_in[7];
  const float* W3  = (const float*)d_in[8];
  const float* b3  = (const float*)d_in[9];
  const float* W_att = (const float*)d_in[10];
  const float* W_tn  = (const float*)d_in[11];
  const float* W_blk = (const float*)d_in[12];
  const float* b_tn  = (const float*)d_in[13];
  const float* W_fc  = (const float*)d_in[14];
  const float* b_fc  = (const float*)d_in[15];
  const float* W_sc  = (const float*)d_in[16];
  const float* b_sc  = (const float*)d_in[17];
  const int E = in_sizes[0];

  char* w = (char*)d_ws;
  size_t off = 0;
  auto alloc = [&](size_t bytes)->void*{ void* p = w + off; off += (bytes + 255)/256*256; return p; };
  // zeroed region (one memset): deg_in, deg_out, cursor, mean, evec
  int*   deg_in  = (int*)alloc((size_t)TWO_N*4);
  int*   deg_out = (int*)alloc((size_t)TWO_N*4);
  int*   cursor  = (int*)alloc((size_t)TWO_N*4);
  float* mean    = (float*)alloc(64*4);
  float* evec    = (float*)alloc(64*4);
  size_t zero_bytes = off;
  int*   row_ptr = (int*)alloc((size_t)TWO_N*4);
  int*   bsum    = (int*)alloc(256*4);
  int*   boff    = (int*)alloc(256*4);
  int*   col     = (int*)alloc((size_t)2*E*4);
  float* x0      = (float*)alloc((size_t)TWO_N*4);
  h2_t*  av      = (h2_t*)alloc((size_t)TWO_N*4);
  _Float16* g3h  = (_Float16*)alloc((size_t)TWO_N*32*2);
  _Float16* f    = (_Float16*)alloc((size_t)TWO_N*32*2);
  float* ctx     = (float*)alloc(64*4);
  int*   tmp     = (int*)g3h;   // scan scratch, dead before g3h is written

  hipMemsetAsync(d_ws, 0, zero_bytes, stream);

  const int nb = (TWO_N + 1023)/1024;   // 196
  k_degrees<<<4096,256,0,stream>>>(s0,dd0,s1,dd1,E,deg_in,deg_out);
  k_scan_block<<<nb,1024,0,stream>>>(deg_in,tmp,bsum);
  k_scan_sums<<<1,256,0,stream>>>(bsum,boff,nb);
  k_make_rowptr<<<(TWO_N+255)/256,256,0,stream>>>(tmp,deg_in,boff,row_ptr);
  k_fill<<<4096,256,0,stream>>>(s0,dd0,s1,dd1,E,row_ptr,cursor,col);

  k_x0<<<(TWO_N+255)/256,256,0,stream>>>(deg_in,deg_out,x0);

  // 512-thread blocks, 8 waves (nodes) per block
  k_g1<<<TWO_N/8,512,0,stream>>>(x0,row_ptr,deg_in,deg_out,col,av);
  k_g2<<<TWO_N/8,512,0,stream>>>(av,row_ptr,deg_in,deg_out,col,W1,b1,W2,b2,W3,g3h);
  k_g3<<<TWO_N/8,512,0,stream>>>(g3h,row_ptr,deg_in,col,b3,f);

  k_colmean<<<512,256,0,stream>>>(f,mean);
  k_ctx<<<1,64,0,stream>>>(mean,W_att,ctx);
  k_scores<<<512,256,0,stream>>>(f,ctx,evec);

  k_final<<<1,64,0,stream>>>(evec,W_tn,W_blk,b_tn,W_fc,b_fc,W_sc,b_sc,(float*)d_out);
}

// Round 4
// 769.872 us; speedup vs baseline: 2.2951x; 1.2674x over previous
//
#include <hip/hip_runtime.h>
#include <math.h>

#define NN 100000
#define TWO_N 200000
#define LDSK 72   // padded k-stride (f16 elems) for h2 LDS bounce (16B-aligned rows)

struct __align__(4) h2_t { _Float16 x, y; };
struct __align__(8) h4_t { _Float16 v[4]; };

typedef __attribute__((ext_vector_type(8))) _Float16 f16x8;
typedef __attribute__((ext_vector_type(4))) _Float16 f16x4;
typedef __attribute__((ext_vector_type(4))) float    f32x4;

__device__ __forceinline__ float sigmoidf_(float x){ return 1.0f/(1.0f+__expf(-x)); }

// ---------------- CSR build (batched: graph0 then graph1) ----------------

__global__ void k_degrees(const int* __restrict__ s0, const int* __restrict__ d0,
                          const int* __restrict__ s1, const int* __restrict__ d1, int E,
                          int* __restrict__ deg_in, int* __restrict__ deg_out){
  for(int i = blockIdx.x*blockDim.x+threadIdx.x; i < 2*E; i += gridDim.x*blockDim.x){
    int g = (i >= E); int le = g ? i - E : i;
    int sv = g ? s1[le] : s0[le];
    int dv = g ? d1[le] : d0[le];
    atomicAdd(&deg_out[g*NN + sv], 1);
    atomicAdd(&deg_in [g*NN + dv], 1);
  }
}

__global__ void k_scan_block(const int* __restrict__ in, int* __restrict__ incl, int* __restrict__ bsum){
  __shared__ int s[1024];
  int i = blockIdx.x*1024 + threadIdx.x;
  int v = (i < TWO_N) ? in[i] : 0;
  s[threadIdx.x] = v; __syncthreads();
  for(int off=1; off<1024; off<<=1){
    int t = (threadIdx.x >= off) ? s[threadIdx.x-off] : 0;
    __syncthreads();
    s[threadIdx.x] += t;
    __syncthreads();
  }
  if(i < TWO_N) incl[i] = s[threadIdx.x];
  if(threadIdx.x == 1023) bsum[blockIdx.x] = s[1023];
}

__global__ void k_scan_sums(const int* __restrict__ bsum, int* __restrict__ boff, int nb){
  __shared__ int s[256];
  int t = threadIdx.x;
  int v = (t < nb) ? bsum[t] : 0;
  s[t] = v; __syncthreads();
  for(int off=1; off<256; off<<=1){
    int u = (t >= off) ? s[t-off] : 0;
    __syncthreads();
    s[t] += u;
    __syncthreads();
  }
  boff[t] = s[t] - v;   // exclusive
}

__global__ void k_make_rowptr(const int* __restrict__ incl, const int* __restrict__ deg,
                              const int* __restrict__ boff, int* __restrict__ row_ptr){
  int i = blockIdx.x*blockDim.x + threadIdx.x;
  if(i < TWO_N) row_ptr[i] = incl[i] - deg[i] + boff[i >> 10];
}

__global__ void k_x0(const int* __restrict__ deg_in, const int* __restrict__ deg_out,
                     float* __restrict__ x0){
  int n = blockIdx.x*blockDim.x + threadIdx.x;
  if(n >= TWO_N) return;
  int dou = deg_out[n];
  x0[n] = (float)deg_in[n] * rsqrtf((float)(dou > 1 ? dou : 1));
}

// fill CSR AND fuse layer-1 scalar aggregation: aggA[dst] += x0[src]
__global__ void k_fill2(const int* __restrict__ s0, const int* __restrict__ d0,
                        const int* __restrict__ s1, const int* __restrict__ d1, int E,
                        const int* __restrict__ row_ptr, int* __restrict__ cursor,
                        int* __restrict__ col, const float* __restrict__ x0,
                        float* __restrict__ aggA){
  for(int i = blockIdx.x*blockDim.x+threadIdx.x; i < 2*E; i += gridDim.x*blockDim.x){
    int g = (i >= E); int le = g ? i - E : i;
    int dv = g ? d1[le] : d0[le];
    int sv = g ? s1[le] : s0[le];
    int gn = g*NN + dv, gs = g*NN + sv;
    int p = atomicAdd(&cursor[gn], 1);
    col[row_ptr[gn] + p] = gs;
    atomicAdd(&aggA[gn], x0[gs]);
  }
}

// av[n] = { a_n = aggA[n]*rs_in(n),  rs_out(n) }  as fp16 pair (4B)
__global__ void k_av(const float* __restrict__ aggA, const int* __restrict__ deg_in,
                     const int* __restrict__ deg_out, h2_t* __restrict__ av){
  int n = blockIdx.x*blockDim.x + threadIdx.x;
  if(n >= TWO_N) return;
  int d = deg_in[n], dou = deg_out[n];
  h2_t o;
  o.x = (_Float16)(aggA[n] * rsqrtf((float)(d > 1 ? d : 1)));
  o.y = (_Float16)rsqrtf((float)(dou > 1 ? dou : 1));
  av[n] = o;
}

// ---------------- layer-2 hinge aggregation (wave per node, lane = j) ----------------
// agg2[n][j] = rs_in(n) * sum_s relu(a_s*W1[j]+b1[j]) * rs_out_s
__global__ void k_g2a(const h2_t* __restrict__ av, const int* __restrict__ row_ptr,
                      const int* __restrict__ deg_in, const int* __restrict__ col,
                      const float* __restrict__ W1, const float* __restrict__ b1,
                      _Float16* __restrict__ agg2){
  __shared__ float W1s[64], b1s[64];
  int t = threadIdx.x;
  if(t < 64){ W1s[t] = W1[t]; b1s[t] = b1[t]; }
  __syncthreads();
  int wid = (blockIdx.x*blockDim.x + t) >> 6;
  int lane = t & 63;
  if(wid >= TWO_N) return;
  int beg = row_ptr[wid], d = deg_in[wid];
  float W1j = W1s[lane], b1j = b1s[lane];
  float acc = 0.f;
  for(int base=0; base<d; base+=64){
    int cnt = min(64, d - base);
    unsigned pk = 0u;
    int idx = base + lane;
    if(idx < d) pk = *(const unsigned*)&av[col[beg+idx]];
    for(int k=0;k<cnt;k++){
      union { unsigned u; h2_t h; } cv; cv.u = __shfl(pk, k);
      float h1 = fmaxf(fmaf((float)cv.h.x, W1j, b1j), 0.f);
      acc = fmaf(h1, (float)cv.h.y, acc);
    }
  }
  float agg = acc * rsqrtf((float)(d > 1 ? d : 1));
  float other = __shfl_xor(agg, 1);
  if(!(lane & 1)){
    h2_t o; o.x = (_Float16)agg; o.y = (_Float16)other;
    *(h2_t*)(agg2 + (size_t)wid*64 + lane) = o;
  }
}

// ---------------- MFMA fused GEMM: h2 = relu(agg2@W2+b2)*rs_out;  g3h = h2@W3 ----------------
// wave handles 16 nodes; 16x16x32 f16 MFMA. k-slot map (identity for gemm1): k = 32*kh + 8*(lane>>4) + e.
// gemm2 phys-k map sigma(j) = 4*(j&15) + (j>>4) so the h2 LDS bounce writes are 8B-contiguous.
__global__ __launch_bounds__(256) void k_mm(
    const _Float16* __restrict__ agg2, const h2_t* __restrict__ av,
    const float* __restrict__ W2, const float* __restrict__ b2,
    const float* __restrict__ W3, _Float16* __restrict__ g3h){
  __shared__ _Float16 h2s[4][16*LDSK];
  int t = threadIdx.x;
  int w = t >> 6, lane = t & 63;
  int g = lane >> 4, c = lane & 15;
  int node0 = (blockIdx.x*4 + w)*16;

  // B2 frags: elem e -> W2[k][n], k = 32kh+8g+e, n = c+16nt
  f16x8 B2[2][4];
  #pragma unroll
  for(int kh=0; kh<2; kh++)
    #pragma unroll
    for(int nt=0; nt<4; nt++)
      #pragma unroll
      for(int e=0;e<8;e++)
        B2[kh][nt][e] = (_Float16)W2[(32*kh + 8*g + e)*64 + c + 16*nt];

  // B3 frags: phys k = 32kh+8g+e -> logical j = (k>>2) + 16*(k&3); n = c+16nt
  f16x8 B3[2][2];
  #pragma unroll
  for(int kh=0; kh<2; kh++)
    #pragma unroll
    for(int nt=0; nt<2; nt++)
      #pragma unroll
      for(int e=0;e<8;e++){
        int kp = 32*kh + 8*g + e;
        int j  = (kp>>2) + 16*(kp&3);
        B3[kh][nt][e] = (_Float16)W3[j*32 + c + 16*nt];
      }

  float b2r[4];
  #pragma unroll
  for(int nt=0;nt<4;nt++) b2r[nt] = b2[c + 16*nt];

  // rs_out for the 4 rows this lane owns in C-layout (rows 4g+r)
  float rs[4];
  #pragma unroll
  for(int r=0;r<4;r++){
    union { unsigned u; h2_t h; } cv;
    cv.u = *(const unsigned*)&av[node0 + 4*g + r];
    rs[r] = (float)cv.h.y;
  }

  // A frags: agg2[node0+c][32kh + 8g + 0..7] — 16B contiguous loads
  f16x8 A[2];
  #pragma unroll
  for(int kh=0;kh<2;kh++)
    A[kh] = *(const f16x8*)(agg2 + (size_t)(node0 + c)*64 + 32*kh + 8*g);

  // GEMM1: D1[m=node][n=j]
  f32x4 acc1[4];
  #pragma unroll
  for(int nt=0;nt<4;nt++){ acc1[nt][0]=0.f; acc1[nt][1]=0.f; acc1[nt][2]=0.f; acc1[nt][3]=0.f; }
  #pragma unroll
  for(int nt=0;nt<4;nt++){
    acc1[nt] = __builtin_amdgcn_mfma_f32_16x16x32_f16(A[0], B2[0][nt], acc1[nt], 0,0,0);
    acc1[nt] = __builtin_amdgcn_mfma_f32_16x16x32_f16(A[1], B2[1][nt], acc1[nt], 0,0,0);
  }

  // epilogue1 -> h2 LDS bounce. value (r,nt): row = 4g+r, j = c+16nt, phys k = 4c+nt.
  _Float16* myh2 = h2s[w];
  #pragma unroll
  for(int r=0;r<4;r++){
    f16x4 pk4;
    #pragma unroll
    for(int nt=0;nt<4;nt++)
      pk4[nt] = (_Float16)(fmaxf(acc1[nt][r] + b2r[nt], 0.f) * rs[r]);
    *(f16x4*)(myh2 + (4*g + r)*LDSK + 4*c) = pk4;
  }
  asm volatile("s_waitcnt lgkmcnt(0)" ::: "memory");

  // A' frags: m = c, phys k = 32kh + 8g + 0..7 — 16B contiguous ds_read
  f16x8 A2[2];
  #pragma unroll
  for(int kh=0;kh<2;kh++)
    A2[kh] = *(const f16x8*)(myh2 + c*LDSK + 32*kh + 8*g);

  f32x4 acc2[2];
  #pragma unroll
  for(int nt=0;nt<2;nt++){ acc2[nt][0]=0.f; acc2[nt][1]=0.f; acc2[nt][2]=0.f; acc2[nt][3]=0.f; }
  #pragma unroll
  for(int nt=0;nt<2;nt++){
    acc2[nt] = __builtin_amdgcn_mfma_f32_16x16x32_f16(A2[0], B3[0][nt], acc2[nt], 0,0,0);
    acc2[nt] = __builtin_amdgcn_mfma_f32_16x16x32_f16(A2[1], B3[1][nt], acc2[nt], 0,0,0);
  }

  // store g3h[node0+4g+r][c+16nt]
  #pragma unroll
  for(int nt=0;nt<2;nt++)
    #pragma unroll
    for(int r=0;r<4;r++)
      g3h[(size_t)(node0 + 4*g + r)*32 + c + 16*nt] = (_Float16)acc2[nt][r];
}

// ---------------- layer3: 32-dim fp16 gather ----------------
__global__ void k_g3(const _Float16* __restrict__ g3h, const int* __restrict__ row_ptr,
                     const int* __restrict__ deg_in, const int* __restrict__ col,
                     const float* __restrict__ b3, _Float16* __restrict__ f){
  int t = threadIdx.x;
  int wid = (blockIdx.x*blockDim.x + t) >> 6;
  int lane = t & 63;
  if(wid >= TWO_N) return;
  int beg = row_ptr[wid], d = deg_in[wid];
  int q = lane >> 3, p = lane & 7;
  float a0=0.f, a1=0.f, a2=0.f, a3=0.f;
  #pragma unroll 2
  for(int e=q; e<d; e+=8){
    int s = col[beg+e];
    float2 v = *(const float2*)(g3h + (size_t)s*32 + p*4);
    union { float f; h2_t h; } u0, u1;
    u0.f = v.x; u1.f = v.y;
    a0 += (float)u0.h.x; a1 += (float)u0.h.y;
    a2 += (float)u1.h.x; a3 += (float)u1.h.y;
  }
  #pragma unroll
  for(int m=8; m<64; m<<=1){
    a0 += __shfl_xor(a0,m); a1 += __shfl_xor(a1,m);
    a2 += __shfl_xor(a2,m); a3 += __shfl_xor(a3,m);
  }
  if(lane < 8){
    float rs = rsqrtf((float)(d > 1 ? d : 1));
    h4_t o;
    o.v[0] = (_Float16)(a0*rs + b3[p*4+0]);
    o.v[1] = (_Float16)(a1*rs + b3[p*4+1]);
    o.v[2] = (_Float16)(a2*rs + b3[p*4+2]);
    o.v[3] = (_Float16)(a3*rs + b3[p*4+3]);
    *(h4_t*)(f + (size_t)wid*32 + p*4) = o;
  }
}

// ---------------- attention (batched) ----------------

__global__ void k_colmean(const _Float16* __restrict__ f, float* __restrict__ mean){
  int g = blockIdx.x >> 8;
  int t = threadIdx.x;
  int p = t & 15;
  int nodeLane = ((blockIdx.x & 255) << 4) | (t >> 4);
  float ax = 0.f, ay = 0.f;
  for(int n=nodeLane; n<NN; n+=4096){
    h2_t v = *(const h2_t*)(f + ((size_t)(g*NN + n))*32 + p*2);
    ax += (float)v.x; ay += (float)v.y;
  }
  __shared__ float sx[256], sy[256];
  sx[t] = ax; sy[t] = ay; __syncthreads();
  if(t < 16){
    float rx = 0.f, ry = 0.f;
    for(int k=0;k<16;k++){ rx += sx[k*16+t]; ry += sy[k*16+t]; }
    atomicAdd(&mean[g*32 + 2*t    ], rx);
    atomicAdd(&mean[g*32 + 2*t + 1], ry);
  }
}

__global__ void k_ctx(const float* __restrict__ mean, const float* __restrict__ W_att,
                      float* __restrict__ ctx){
  int t = threadIdx.x;   // 64 threads: 2 graphs x 32 dims
  int g = t >> 5, d = t & 31;
  float acc = 0.f;
  for(int i=0;i<32;i++) acc += (mean[g*32+i] * (1.0f/(float)NN)) * W_att[i*32 + d];
  ctx[t] = tanhf(acc);
}

__global__ void k_scores(const _Float16* __restrict__ f, const float* __restrict__ ctx,
                         float* __restrict__ evec){
  int g = blockIdx.x >> 8;
  int t = threadIdx.x;
  int p = t & 15;
  int nodeLane = ((blockIdx.x & 255) << 4) | (t >> 4);
  float cx = ctx[g*32 + 2*p], cy = ctx[g*32 + 2*p + 1];
  float ax = 0.f, ay = 0.f;
  for(int n=nodeLane; n<NN; n+=4096){
    h2_t v = *(const h2_t*)(f + ((size_t)(g*NN + n))*32 + p*2);
    float vx = (float)v.x, vy = (float)v.y;
    float dt = vx*cx + vy*cy;
    dt += __shfl_xor(dt,1); dt += __shfl_xor(dt,2);
    dt += __shfl_xor(dt,4); dt += __shfl_xor(dt,8);
    float sc = sigmoidf_(dt);
    ax += vx*sc; ay += vy*sc;
  }
  __shared__ float sx[256], sy[256];
  sx[t] = ax; sy[t] = ay; __syncthreads();
  if(t < 16){
    float rx = 0.f, ry = 0.f;
    for(int k=0;k<16;k++){ rx += sx[k*16+t]; ry += sy[k*16+t]; }
    atomicAdd(&evec[g*32 + 2*t    ], rx);
    atomicAdd(&evec[g*32 + 2*t + 1], ry);
  }
}

// ---------------- tiny head ----------------

__global__ void k_final(const float* __restrict__ evec,
                        const float* __restrict__ W_tn, const float* __restrict__ W_blk,
                        const float* __restrict__ b_tn, const float* __restrict__ W_fc,
                        const float* __restrict__ b_fc, const float* __restrict__ W_sc,
                        const float* __restrict__ b_sc, float* __restrict__ out){
  __shared__ float se0[32], se1[32], s_s[16], s2[16];
  int t = threadIdx.x;  // 64 threads
  if(t < 32){ se0[t] = evec[t]; se1[t] = evec[32 + t]; }
  __syncthreads();
  if(t < 16){
    float sc = 0.f;
    for(int i=0;i<32;i++){
      float a = se0[i];
      for(int j=0;j<32;j++) sc += a * W_tn[(i*32 + j)*16 + t] * se1[j];
    }
    float bl = 0.f;
    for(int k=0;k<32;k++) bl += W_blk[t*64 + k]      * se0[k];
    for(int k=0;k<32;k++) bl += W_blk[t*64 + 32 + k] * se1[k];
    s_s[t] = fmaxf(sc + bl + b_tn[t], 0.f);
  }
  __syncthreads();
  if(t < 16){
    float a = 0.f;
    for(int k=0;k<16;k++) a += s_s[k]*W_fc[k*16 + t];
    s2[t] = fmaxf(a + b_fc[t], 0.f);
  }
  __syncthreads();
  if(t == 0){
    float a = 0.f;
    for(int k=0;k<16;k++) a += s2[k]*W_sc[k];
    out[0] = sigmoidf_(a + b_sc[0]);
  }
}

// ---------------- launch ----------------

extern "C" void kernel_launch(void* const* d_in, const int* in_sizes, int n_in,
                              void* d_out, int out_size, void* d_ws, size_t ws_size,
                              hipStream_t stream){
  const int* s0 = (const int*)d_in[0];
  const int* dd0 = (const int*)d_in[1];
  const int* s1 = (const int*)d_in[2];
  const int* dd1 = (const int*)d_in[3];
  const float* W1  = (const float*)d_in[4];
  const float* b1  = (const float*)d_in[5];
  const float* W2  = (const float*)d_in[6];
  const float* b2  = (const float*)d_in[7];
  const float* W3  = (const float*)d_in[8];
  const float* b3  = (const float*)d_in[9];
  const float* W_att = (const float*)d_in[10];
  const float* W_tn  = (const float*)d_in[11];
  const float* W_blk = (const float*)d_in[12];
  const float* b_tn  = (const float*)d_in[13];
  const float* W_fc  = (const float*)d_in[14];
  const float* b_fc  = (const float*)d_in[15];
  const float* W_sc  = (const float*)d_in[16];
  const float* b_sc  = (const float*)d_in[17];
  const int E = in_sizes[0];

  char* w = (char*)d_ws;
  size_t off = 0;
  auto alloc = [&](size_t bytes)->void*{ void* p = w + off; off += (bytes + 255)/256*256; return p; };
  // zeroed region (one memset): deg_in, deg_out, cursor, aggA, mean, evec
  int*   deg_in  = (int*)alloc((size_t)TWO_N*4);
  int*   deg_out = (int*)alloc((size_t)TWO_N*4);
  int*   cursor  = (int*)alloc((size_t)TWO_N*4);
  float* aggA    = (float*)alloc((size_t)TWO_N*4);
  float* mean    = (float*)alloc(64*4);
  float* evec    = (float*)alloc(64*4);
  size_t zero_bytes = off;
  int*   row_ptr = (int*)alloc((size_t)TWO_N*4);
  int*   bsum    = (int*)alloc(256*4);
  int*   boff    = (int*)alloc(256*4);
  int*   col     = (int*)alloc((size_t)2*E*4);
  float* x0      = (float*)alloc((size_t)TWO_N*4);
  h2_t*  av      = (h2_t*)alloc((size_t)TWO_N*4);
  _Float16* agg2 = (_Float16*)alloc((size_t)TWO_N*64*2);   // 25.6 MB
  _Float16* g3h  = (_Float16*)alloc((size_t)TWO_N*32*2);
  float* ctx     = (float*)alloc(64*4);
  int*   tmp     = (int*)agg2;              // scan scratch, dead before agg2 written
  _Float16* f    = agg2;                    // f aliases agg2 (agg2 dead after k_mm)

  hipMemsetAsync(d_ws, 0, zero_bytes, stream);

  const int nb = (TWO_N + 1023)/1024;   // 196
  k_degrees<<<4096,256,0,stream>>>(s0,dd0,s1,dd1,E,deg_in,deg_out);
  k_scan_block<<<nb,1024,0,stream>>>(deg_in,tmp,bsum);
  k_scan_sums<<<1,256,0,stream>>>(bsum,boff,nb);
  k_make_rowptr<<<(TWO_N+255)/256,256,0,stream>>>(tmp,deg_in,boff,row_ptr);
  k_x0<<<(TWO_N+255)/256,256,0,stream>>>(deg_in,deg_out,x0);
  k_fill2<<<4096,256,0,stream>>>(s0,dd0,s1,dd1,E,row_ptr,cursor,col,x0,aggA);
  k_av<<<(TWO_N+255)/256,256,0,stream>>>(aggA,deg_in,deg_out,av);

  k_g2a<<<TWO_N/8,512,0,stream>>>(av,row_ptr,deg_in,col,W1,b1,agg2);
  k_mm<<<TWO_N/64,256,0,stream>>>(agg2,av,W2,b2,W3,g3h);
  k_g3<<<TWO_N/8,512,0,stream>>>(g3h,row_ptr,deg_in,col,b3,f);

  k_colmean<<<512,256,0,stream>>>(f,mean);
  k_ctx<<<1,64,0,stream>>>(mean,W_att,ctx);
  k_scores<<<512,256,0,stream>>>(f,ctx,evec);

  k_final<<<1,64,0,stream>>>(evec,W_tn,W_blk,b_tn,W_fc,b_fc,W_sc,b_sc,(float*)d_out);
}